// Round 18
// baseline (729.067 us; speedup 1.0000x reference)
//
#include <hip/hip_runtime.h>
#include <cstdint>

// ---------------------------------------------------------------------------
// Red-black SOR Laplace solver, persistent kernel. Round 18 = r17's dense
// minimal exchange with TAG-IN-DATA synchronization (no flags, no staging).
// Each dyn value is published as u64 (tag<<32)|f32bits into a 4-generation
// channel buffer ch[t&3][iface][side][slot]; the consumer polls its slot
// until tag == wanted (exact match rejects stale gens and 0xAA poison).
//   black(t): cross = red(t-1) values -> poll ch[(t-1)&3], want t-1
//   red(t):   cross = black(t) values -> poll ch[t&3],     want t
// Generation reuse safety: writer of gen t+4 passed its start-of-iteration
// dv-ring poll (all blocks finished t+2) => all reads of gen-t slots (latest
// reader: black(t+1)) are complete. Ring poll also bounds global skew <= 2
// (ring depth 8 ample). Stop: depth-8 dv ring, fixed-point payload, lagged
// exact stop at g=t-2 -> uniform break; reports iters=149 and dv(149)
// exactly (1 extra iteration computed). Values, op order, and the dv path
// are bit-identical to r17 (passed, iters=149).
// ---------------------------------------------------------------------------

#define NBLK 132
#define NTHR 512
#define NW   (NTHR / 64)

constexpr int NJK   = 66;
constexpr int PLANE = 66 * 66;          // 4356
constexpr int NI    = 132;
constexpr int CAPL  = 2048;             // max gm per color per plane
constexpr int SLOT  = 512;              // dense slots per iface side (max ~320)
constexpr int NIF   = 133;              // interfaces 0..132
constexpr int NOUT  = 2 * 64 * 64 * 64; // 524288
constexpr size_t CHGEN = (size_t)NIF * 2 * SLOT;   // u64s per generation
// ctrl 128B lines: [0..127] dv rings 0..7 (16 lines each); [128..143]
// startup barrier.
constexpr int CTRL_U64 = 144 * 16;
constexpr unsigned long long CNT1   = 1ull << 44;
constexpr unsigned long long MASK44 = CNT1 - 1ull;

__global__ void sor_init_ctrl(unsigned long long* ctrl) {
  for (int i = threadIdx.x; i < CTRL_U64; i += blockDim.x) ctrl[i] = 0ull;
}

__device__ __forceinline__ unsigned long long cloadu(const unsigned long long* p) {
  return __hip_atomic_load(p, __ATOMIC_RELAXED, __HIP_MEMORY_SCOPE_AGENT);
}
__device__ __forceinline__ void cstoreu(unsigned long long* p, unsigned long long v) {
  __hip_atomic_store(p, v, __ATOMIC_RELAXED, __HIP_MEMORY_SCOPE_AGENT);
}
__device__ __forceinline__ unsigned long long packv(unsigned tag, float v) {
  return ((unsigned long long)tag << 32) | (unsigned long long)__float_as_uint(v);
}
__device__ __forceinline__ float pollv(const unsigned long long* p, unsigned want) {
  unsigned long long u = cloadu(p);
  while ((unsigned)(u >> 32) != want) {
    __builtin_amdgcn_s_sleep(1);
    u = cloadu(p);
  }
  return __uint_as_float((unsigned)u);
}

// padded flat coords -> original image flat index, or -1 if pad voxel
__device__ __forceinline__ int pad_label_idx(int ii, int jj, int kk) {
  int b  = (ii >= 66) ? 1 : 0;
  int pz = ii - 66 * b;
  if (pz < 1 || pz > 64 || jj < 1 || jj > 64 || kk < 1 || kk > 64) return -1;
  return ((b * 64 + (pz - 1)) * 64 + (jj - 1)) * 64 + (kk - 1);
}

__global__ __launch_bounds__(NTHR, 1)
void sor_main(const float* __restrict__ img,
              unsigned long long* __restrict__ ch,
              unsigned long long* __restrict__ ctrl,
              float* __restrict__ out) {
  __shared__ double P1[PLANE];                 // own plane, f64
  __shared__ unsigned short tmpm[PLANE];       // dense slot map, dir z-1
  __shared__ unsigned short tmpp[PLANE];       // dense slot map, dir z+1
  __shared__ unsigned short lsB[CAPL], lsR[CAPL];
  __shared__ unsigned auxB[CAPL], auxR[CAPL];  // codem | (codep<<16)
  __shared__ unsigned wsum[NW], woff[NW];
  __shared__ unsigned tot;
  __shared__ double redw[NW];
  __shared__ unsigned long long prevs[8];
  __shared__ double sh_dv;

  const int tid = threadIdx.x, bid = blockIdx.x;
  const int lane = tid & 63, wid = tid >> 6;
  const int z = bid;

  // ---- init own plane in LDS ----
  for (int o = tid; o < PLANE; o += NTHR) {
    int j = o / NJK, k = o - j * NJK;
    int li = pad_label_idx(z, j, k);
    float L = (li >= 0) ? img[li] : 0.0f;
    P1[o] = (L == 3.0f) ? 1.0 : 0.0;
  }
  if (tid < 8) prevs[tid] = 0ull;

  const int CH = (PLANE + NTHR - 1) / NTHR;
  // ---- passes A/B: dense slot maps per direction (both colors, o-order) --
  for (int dir = 0; dir < 2; ++dir) {
    const int zx = (dir == 0) ? (z - 1) : (z + 1);
    unsigned short* tmp = (dir == 0) ? tmpm : tmpp;
    int c0 = tid * CH;
    int c1 = (c0 + CH < PLANE) ? (c0 + CH) : PLANE;
    unsigned cnt = 0;
    for (int o = c0; o < c1; ++o) {
      int j = o / NJK, k = o - j * NJK;
      int li = pad_label_idx(z, j, k);
      float L = (li >= 0) ? img[li] : 0.0f;
      if (L != 1.0f) continue;
      int lx = pad_label_idx(zx, j, k);
      float Lx = (lx >= 0) ? img[lx] : 0.0f;
      if (Lx == 1.0f) cnt++;
    }
    unsigned incl = cnt;
    #pragma unroll
    for (int m = 1; m < 64; m <<= 1) {
      unsigned t = __shfl_up(incl, m, 64);
      if (lane >= m) incl += t;
    }
    __syncthreads();
    if (lane == 63) wsum[wid] = incl;
    __syncthreads();
    if (tid == 0) {
      unsigned a = 0;
      for (int w = 0; w < NW; ++w) { unsigned c = wsum[w]; woff[w] = a; a += c; }
      tot = a;
    }
    __syncthreads();
    unsigned p = (incl - cnt) + woff[wid];
    for (int o = c0; o < c1; ++o) {
      int j = o / NJK, k = o - j * NJK;
      int li = pad_label_idx(z, j, k);
      float L = (li >= 0) ? img[li] : 0.0f;
      if (L != 1.0f) continue;
      int lx = pad_label_idx(zx, j, k);
      float Lx = (lx >= 0) ? img[lx] : 0.0f;
      if (Lx == 1.0f) tmp[o] = (unsigned short)(p++);
    }
    __syncthreads();
  }

  // ---- pass C: per-color gm lists + aux codes (stable o-order) ----
  int cntB = 0, cntR = 0;
  for (int cb = 0; cb < 2; ++cb) {
    unsigned short* list = (cb == 0) ? lsB : lsR;
    unsigned* aux        = (cb == 0) ? auxB : auxR;
    int c0 = tid * CH;
    int c1 = (c0 + CH < PLANE) ? (c0 + CH) : PLANE;
    unsigned cnt = 0;
    for (int o = c0; o < c1; ++o) {
      int j = o / NJK, k = o - j * NJK;
      if (((z + j + k) & 1) != cb) continue;
      int li = pad_label_idx(z, j, k);
      float L = (li >= 0) ? img[li] : 0.0f;
      if (L == 1.0f) cnt++;
    }
    unsigned incl = cnt;
    #pragma unroll
    for (int m = 1; m < 64; m <<= 1) {
      unsigned t = __shfl_up(incl, m, 64);
      if (lane >= m) incl += t;
    }
    __syncthreads();
    if (lane == 63) wsum[wid] = incl;
    __syncthreads();
    if (tid == 0) {
      unsigned a = 0;
      for (int w = 0; w < NW; ++w) { unsigned c = wsum[w]; woff[w] = a; a += c; }
      tot = a;
    }
    __syncthreads();
    unsigned p = (incl - cnt) + woff[wid];
    for (int o = c0; o < c1; ++o) {
      int j = o / NJK, k = o - j * NJK;
      if (((z + j + k) & 1) != cb) continue;
      int li = pad_label_idx(z, j, k);
      float L = (li >= 0) ? img[li] : 0.0f;
      if (L != 1.0f) continue;
      int lm = pad_label_idx(z - 1, j, k);
      float Lm = (lm >= 0) ? img[lm] : 0.0f;
      int lp = pad_label_idx(z + 1, j, k);
      float Lp = (lp >= 0) ? img[lp] : 0.0f;
      unsigned cm = (Lm == 1.0f) ? (unsigned)tmpm[o]
                                 : (0x8000u | (Lm == 3.0f ? 1u : 0u));
      unsigned cp = (Lp == 1.0f) ? (unsigned)tmpp[o]
                                 : (0x8000u | (Lp == 3.0f ? 1u : 0u));
      list[p] = (unsigned short)o;
      aux[p]  = cm | (cp << 16);
      p++;
    }
    __syncthreads();
    if (cb == 0) cntB = (int)tot; else cntR = (int)tot;
  }

  // ---- channel offsets (iface z: planes z-1|z; iface z+1: z|z+1) ----
  const size_t offRm = ((size_t)z * 2 + 0) * SLOT;        // read from z-1 (L)
  const size_t offPm = ((size_t)z * 2 + 1) * SLOT;        // my publish (H)
  const size_t offRp = ((size_t)(z + 1) * 2 + 1) * SLOT;  // read from z+1 (H)
  const size_t offPp = ((size_t)(z + 1) * 2 + 0) * SLOT;  // my publish (L)

  // ---- prefill gen-0 red dyn slots with tag 0 (initial red values) ----
  for (int p = tid; p < cntR; p += NTHR) {
    unsigned u = auxR[p];
    unsigned cm = u & 0xFFFFu, cp = u >> 16;
    float v = (float)P1[(int)lsR[p]];
    if (!(cm & 0x8000u)) cstoreu(&ch[offPm + cm], packv(0u, v));
    if (!(cp & 0x8000u)) cstoreu(&ch[offPp + cp], packv(0u, v));
  }
  __syncthreads();                         // drain prefill
  // ---- startup barrier (count-only, 16 lines) ----
  if (tid == 0)
    __hip_atomic_fetch_add(&ctrl[(128u + (unsigned)(bid & 15)) * 16u], 1ull,
                           __ATOMIC_RELAXED, __HIP_MEMORY_SCOPE_AGENT);
  if (tid < 16) {
    for (;;) {
      unsigned long long v = cloadu(&ctrl[(128u + (unsigned)tid) * 16u]);
      v += __shfl_xor(v, 1, 64);  v += __shfl_xor(v, 2, 64);
      v += __shfl_xor(v, 4, 64);  v += __shfl_xor(v, 8, 64);
      if (v >= (unsigned long long)NBLK) break;
      __builtin_amdgcn_s_sleep(1);
    }
  }
  __syncthreads();

  const double WOPT = 2.0 / (1.0 + 3.14159265358979323846 / 66.0);

  int itout = 0;
  double dvout = 0.0;

  for (int t = 1; t <= 555; ++t) {
    // ---- start-of-iter: overlapped ring poll + uniform lagged stop ----
    if (t > 2) {
      const int g = t - 2;
      if (wid == 0 && lane < 16) {
        const int r = g & 7;
        const unsigned n = ((unsigned)g + 7u) >> 3;
        const unsigned long long t64 =
            ((unsigned long long)NBLK * n) << 44;
        unsigned long long v;
        for (;;) {
          v = cloadu(&ctrl[((unsigned)r * 16u + (unsigned)lane) * 16u]);
          v += __shfl_xor(v, 1, 64);  v += __shfl_xor(v, 2, 64);
          v += __shfl_xor(v, 4, 64);  v += __shfl_xor(v, 8, 64);
          if (v >= t64) break;
          __builtin_amdgcn_s_sleep(1);
        }
        if (lane == 0) {
          unsigned long long cum = v & MASK44;
          sh_dv = (double)(cum - prevs[r]) * (1.0 / 1048576.0);
          prevs[r] = cum;
        }
      }
      __syncthreads();
      double dvg = sh_dv;
      if (!((dvg >= 0.05) && ((t - 2) <= 500))) {
        itout = t - 2; dvout = dvg; break;
      }
    }

    unsigned long long* __restrict__ chW = ch + (size_t)(t & 3) * CHGEN;
    const unsigned long long* __restrict__ chB =
        ch + (size_t)((t - 1) & 3) * CHGEN;

    double acc = 0.0;
    // ================= BLACK sweep (cross: red tag t-1) =================
    for (int p = tid; p < cntB; p += NTHR) {
      const int o = (int)lsB[p];
      const unsigned u = auxB[p];
      const unsigned cm = u & 0xFFFFu, cp = u >> 16;
      double fzm = (cm & 0x8000u) ? (double)(cm & 1u)
                                  : (double)pollv(&chB[offRm + cm],
                                                  (unsigned)(t - 1));
      double fzp = (cp & 0x8000u) ? (double)(cp & 1u)
                                  : (double)pollv(&chB[offRp + cp],
                                                  (unsigned)(t - 1));
      double xi = P1[o];
      double nb = ((((P1[o - 1] + P1[o + 1]) + P1[o - NJK]) + P1[o + NJK])
                  + fzm) + fzp;
      double adj = (WOPT * (nb - 6.0 * xi)) / 6.0;
      double v = xi + adj;
      P1[o] = v;
      if (!(cm & 0x8000u)) cstoreu(&chW[offPm + cm], packv((unsigned)t, (float)v));
      if (!(cp & 0x8000u)) cstoreu(&chW[offPp + cp], packv((unsigned)t, (float)v));
      acc += fabs(adj);
    }
    __syncthreads();                       // black LDS updates visible

    // ================= RED sweep (cross: black tag t) =================
    for (int p = tid; p < cntR; p += NTHR) {
      const int o = (int)lsR[p];
      const unsigned u = auxR[p];
      const unsigned cm = u & 0xFFFFu, cp = u >> 16;
      double fzm = (cm & 0x8000u) ? (double)(cm & 1u)
                                  : (double)pollv(&chW[offRm + cm], (unsigned)t);
      double fzp = (cp & 0x8000u) ? (double)(cp & 1u)
                                  : (double)pollv(&chW[offRp + cp], (unsigned)t);
      double xi = P1[o];
      double nb = ((((P1[o - 1] + P1[o + 1]) + P1[o - NJK]) + P1[o + NJK])
                  + fzm) + fzp;
      double adj = (WOPT * (nb - 6.0 * xi)) / 6.0;
      double v = xi + adj;
      P1[o] = v;
      if (!(cm & 0x8000u)) cstoreu(&chW[offPm + cm], packv((unsigned)t, (float)v));
      if (!(cp & 0x8000u)) cstoreu(&chW[offPp + cp], packv((unsigned)t, (float)v));
      acc += fabs(adj);
    }

    // ---- block dv reduce (fixed order) + ring post ----
    double a = acc;
    #pragma unroll
    for (int m = 32; m >= 1; m >>= 1) a += __shfl_xor(a, m, 64);
    if (lane == 0) redw[wid] = a;
    __syncthreads();                       // redw ready; publishes issued
    if (tid == 0) {
      double s = redw[0];
      #pragma unroll
      for (int w = 1; w < NW; ++w) s += redw[w];
      __hip_atomic_fetch_add(
          &ctrl[(((unsigned)t & 7u) * 16u + (unsigned)(bid & 15)) * 16u],
          CNT1 + (unsigned long long)(s * 1048576.0 + 0.5),
          __ATOMIC_RELAXED, __HIP_MEMORY_SCOPE_AGENT);
    }
  }

  // ---- epilogue: lap straight from LDS (crop pad), + iters + dv ----
  {
    const int vb = (z >= 66) ? 1 : 0;
    const int pz = z - 66 * vb;
    if (pz >= 1 && pz <= 64) {
      float* ob = out + ((size_t)vb * 64 + (pz - 1)) * 4096;
      for (int t2 = tid; t2 < 4096; t2 += NTHR) {
        int jj = t2 >> 6, kk = t2 & 63;
        ob[t2] = (float)P1[NJK * (jj + 1) + (kk + 1)];
      }
    }
    if (z == 0 && tid == 0) {
      out[NOUT]     = (float)itout;
      out[NOUT + 1] = (float)dvout;
    }
  }
}

extern "C" void kernel_launch(void* const* d_in, const int* in_sizes, int n_in,
                              void* d_out, int out_size, void* d_ws, size_t ws_size,
                              hipStream_t stream) {
  const float* img = (const float*)d_in[0];
  float* out = (float*)d_out;
  unsigned long long* chbuf = (unsigned long long*)d_ws;     // 4 gens
  unsigned long long* ctrl  = chbuf + 4 * CHGEN;

  sor_init_ctrl<<<1, 256, 0, stream>>>(ctrl);
  sor_main<<<NBLK, NTHR, 0, stream>>>(img, chbuf, ctrl, out);
}

// Round 19
// 609.302 us; speedup vs baseline: 1.1966x; 1.1966x over previous
//
#include <hip/hip_runtime.h>
#include <cstdint>

// ---------------------------------------------------------------------------
// Red-black SOR Laplace solver, persistent kernel. Round 19 = round 14's
// EXACT control flow (132 blocks, 1024 thr, neighbor flag chain, depth-8 dv
// ring, parallel start-waits, lagged exact stop) with ONLY the exchange
// addressing changed: packed half-planes (68 lines/side) -> dense slots
// (~10 lines/side), per r17's symmetric-set construction.
// Per interface i (planes i-1 | i): both sides enumerate {o: gm(i-1,o) &&
// gm(i,o)} in identical o-order -> read slot == publish slot. Each gm voxel
// carries u32 aux = code(z-1) | code(z+1)<<16; code = dense slot if cross-gm
// else 0x8000|const(0/1). Sweeps read crosses per-voxel (plain loads, data
// guaranteed by the same flag waits as r14) and publish dyn values inline.
// Values bit-identical to r14 (f32-published dyn values; const 0/1 equal to
// r14's never-updated prefilled entries); same op order; same dv fixed-point
// path -> iters = 149, dv(149) exact; 1 extra iteration computed.
// ---------------------------------------------------------------------------

#define NBLK 132
#define NTHR 1024
#define NW   (NTHR / 64)

constexpr int NJK   = 66;
constexpr int PLANE = 66 * 66;          // 4356
constexpr int NI    = 132;
constexpr int CAPL  = 2048;             // max gm per color per plane
constexpr int SLOT  = 768;              // dense slots per iface side
constexpr int NIF   = 133;              // interfaces 0..132
constexpr int NOUT  = 2 * 64 * 64 * 64; // 524288
// ctrl 128B lines: [0..127] dv rings 0..7 (16 lines each); [128..143]
// startup barrier; [144..275] black flags (144+b); [276..407] red flags.
constexpr int CTRL_U64 = 408 * 16;
constexpr unsigned long long CNT1   = 1ull << 44;
constexpr unsigned long long MASK44 = CNT1 - 1ull;

__global__ void sor_init_ctrl(unsigned long long* ctrl) {
  for (int i = threadIdx.x; i < CTRL_U64; i += blockDim.x) ctrl[i] = 0ull;
}

__device__ __forceinline__ float cloadf(const float* p) {
  return __hip_atomic_load(p, __ATOMIC_RELAXED, __HIP_MEMORY_SCOPE_AGENT);
}
__device__ __forceinline__ void cstoref(float* p, float v) {
  __hip_atomic_store(p, v, __ATOMIC_RELAXED, __HIP_MEMORY_SCOPE_AGENT);
}
__device__ __forceinline__ unsigned long long cloadu(const unsigned long long* p) {
  return __hip_atomic_load(p, __ATOMIC_RELAXED, __HIP_MEMORY_SCOPE_AGENT);
}
__device__ __forceinline__ void cstoreu(unsigned long long* p, unsigned long long v) {
  __hip_atomic_store(p, v, __ATOMIC_RELAXED, __HIP_MEMORY_SCOPE_AGENT);
}

// padded flat coords -> original image flat index, or -1 if pad voxel
__device__ __forceinline__ int pad_label_idx(int ii, int jj, int kk) {
  int b  = (ii >= 66) ? 1 : 0;
  int pz = ii - 66 * b;
  if (pz < 1 || pz > 64 || jj < 1 || jj > 64 || kk < 1 || kk > 64) return -1;
  return ((b * 64 + (pz - 1)) * 64 + (jj - 1)) * 64 + (kk - 1);
}

__global__ __launch_bounds__(NTHR, 1)
void sor_main(const float* __restrict__ img,
              float* __restrict__ pb0, float* __restrict__ pb1,
              float* __restrict__ pr0, float* __restrict__ pr1,
              unsigned long long* __restrict__ ctrl,
              float* __restrict__ out) {
  __shared__ double P1[PLANE];                 // own plane, f64
  __shared__ unsigned short tmpm[PLANE];       // dense slot map, dir z-1
  __shared__ unsigned short tmpp[PLANE];       // dense slot map, dir z+1
  __shared__ unsigned short lsB[CAPL], lsR[CAPL];
  __shared__ unsigned auxB[CAPL], auxR[CAPL];  // codem | (codep<<16)
  __shared__ unsigned wsum[NW], woff[NW];
  __shared__ unsigned tot;
  __shared__ double redw[NW];
  __shared__ unsigned long long prevs[8];
  __shared__ double sh_dv;

  const int tid = threadIdx.x, bid = blockIdx.x;
  const int lane = tid & 63, wid = tid >> 6;
  const int z = bid;

  // ---- init own plane in LDS ----
  for (int o = tid; o < PLANE; o += NTHR) {
    int j = o / NJK, k = o - j * NJK;
    int li = pad_label_idx(z, j, k);
    float L = (li >= 0) ? img[li] : 0.0f;
    P1[o] = (L == 3.0f) ? 1.0 : 0.0;
  }
  if (tid < 8) prevs[tid] = 0ull;

  const int CH = (PLANE + NTHR - 1) / NTHR;
  // ---- passes A/B: dense slot maps per direction (both colors, o-order) --
  for (int dir = 0; dir < 2; ++dir) {
    const int zx = (dir == 0) ? (z - 1) : (z + 1);
    unsigned short* tmp = (dir == 0) ? tmpm : tmpp;
    int c0 = tid * CH;
    int c1 = (c0 + CH < PLANE) ? (c0 + CH) : PLANE;
    unsigned cnt = 0;
    for (int o = c0; o < c1; ++o) {
      int j = o / NJK, k = o - j * NJK;
      int li = pad_label_idx(z, j, k);
      float L = (li >= 0) ? img[li] : 0.0f;
      if (L != 1.0f) continue;
      int lx = pad_label_idx(zx, j, k);
      float Lx = (lx >= 0) ? img[lx] : 0.0f;
      if (Lx == 1.0f) cnt++;
    }
    unsigned incl = cnt;
    #pragma unroll
    for (int m = 1; m < 64; m <<= 1) {
      unsigned t = __shfl_up(incl, m, 64);
      if (lane >= m) incl += t;
    }
    __syncthreads();
    if (lane == 63) wsum[wid] = incl;
    __syncthreads();
    if (tid == 0) {
      unsigned a = 0;
      for (int w = 0; w < NW; ++w) { unsigned c = wsum[w]; woff[w] = a; a += c; }
      tot = a;
    }
    __syncthreads();
    unsigned p = (incl - cnt) + woff[wid];
    for (int o = c0; o < c1; ++o) {
      int j = o / NJK, k = o - j * NJK;
      int li = pad_label_idx(z, j, k);
      float L = (li >= 0) ? img[li] : 0.0f;
      if (L != 1.0f) continue;
      int lx = pad_label_idx(zx, j, k);
      float Lx = (lx >= 0) ? img[lx] : 0.0f;
      if (Lx == 1.0f) tmp[o] = (unsigned short)(p++);
    }
    __syncthreads();
  }

  // ---- pass C: per-color gm lists + aux codes (stable o-order) ----
  int cntB = 0, cntR = 0;
  for (int cb = 0; cb < 2; ++cb) {
    unsigned short* list = (cb == 0) ? lsB : lsR;
    unsigned* aux        = (cb == 0) ? auxB : auxR;
    int c0 = tid * CH;
    int c1 = (c0 + CH < PLANE) ? (c0 + CH) : PLANE;
    unsigned cnt = 0;
    for (int o = c0; o < c1; ++o) {
      int j = o / NJK, k = o - j * NJK;
      if (((z + j + k) & 1) != cb) continue;
      int li = pad_label_idx(z, j, k);
      float L = (li >= 0) ? img[li] : 0.0f;
      if (L == 1.0f) cnt++;
    }
    unsigned incl = cnt;
    #pragma unroll
    for (int m = 1; m < 64; m <<= 1) {
      unsigned t = __shfl_up(incl, m, 64);
      if (lane >= m) incl += t;
    }
    __syncthreads();
    if (lane == 63) wsum[wid] = incl;
    __syncthreads();
    if (tid == 0) {
      unsigned a = 0;
      for (int w = 0; w < NW; ++w) { unsigned c = wsum[w]; woff[w] = a; a += c; }
      tot = a;
    }
    __syncthreads();
    unsigned p = (incl - cnt) + woff[wid];
    for (int o = c0; o < c1; ++o) {
      int j = o / NJK, k = o - j * NJK;
      if (((z + j + k) & 1) != cb) continue;
      int li = pad_label_idx(z, j, k);
      float L = (li >= 0) ? img[li] : 0.0f;
      if (L != 1.0f) continue;
      int lm = pad_label_idx(z - 1, j, k);
      float Lm = (lm >= 0) ? img[lm] : 0.0f;
      int lp = pad_label_idx(z + 1, j, k);
      float Lp = (lp >= 0) ? img[lp] : 0.0f;
      unsigned cm = (Lm == 1.0f) ? (unsigned)tmpm[o]
                                 : (0x8000u | (Lm == 3.0f ? 1u : 0u));
      unsigned cp = (Lp == 1.0f) ? (unsigned)tmpp[o]
                                 : (0x8000u | (Lp == 3.0f ? 1u : 0u));
      list[p] = (unsigned short)o;
      aux[p]  = cm | (cp << 16);
      p++;
    }
    __syncthreads();
    if (cb == 0) cntB = (int)tot; else cntR = (int)tot;
  }

  // ---- channel offsets (iface z: planes z-1|z; iface z+1: z|z+1) ----
  const size_t offRm = ((size_t)z * 2 + 0) * SLOT;        // read from z-1 (L)
  const size_t offPm = ((size_t)z * 2 + 1) * SLOT;        // my publish (H)
  const size_t offRp = ((size_t)(z + 1) * 2 + 1) * SLOT;  // read from z+1 (H)
  const size_t offPp = ((size_t)(z + 1) * 2 + 0) * SLOT;  // my publish (L)

  // ---- prefill pr0 dyn slots with initial red values (gm init = 0) ----
  for (int p = tid; p < cntR; p += NTHR) {
    unsigned u = auxR[p];
    unsigned cm = u & 0xFFFFu, cp = u >> 16;
    if (!(cm & 0x8000u)) cstoref(&pr0[offPm + cm], 0.0f);
    if (!(cp & 0x8000u)) cstoref(&pr0[offPp + cp], 0.0f);
  }
  __syncthreads();                         // drain prefill
  // ---- startup barrier (count-only, 16 lines) ----
  if (tid == 0)
    __hip_atomic_fetch_add(&ctrl[(128u + (unsigned)(bid & 15)) * 16u], 1ull,
                           __ATOMIC_RELAXED, __HIP_MEMORY_SCOPE_AGENT);
  if (tid < 16) {
    for (;;) {
      unsigned long long v = cloadu(&ctrl[(128u + (unsigned)tid) * 16u]);
      v += __shfl_xor(v, 1, 64);  v += __shfl_xor(v, 2, 64);
      v += __shfl_xor(v, 4, 64);  v += __shfl_xor(v, 8, 64);
      if (v >= (unsigned long long)NBLK) break;
      __builtin_amdgcn_s_sleep(1);
    }
  }
  __syncthreads();

  const double WOPT = 2.0 / (1.0 + 3.14159265358979323846 / 66.0);

  int itout = 0;
  double dvout = 0.0;

  for (int t = 1; t <= 555; ++t) {
    const float* __restrict__ prold = (t & 1) ? pr0 : pr1;  // pr[(t-1)&1]
    float* __restrict__ pbcur       = (t & 1) ? pb1 : pb0;  // pb[t&1]
    float* __restrict__ prcur       = (t & 1) ? pr1 : pr0;  // pr[t&1]

    // ---- start-of-iter parallel waits + lagged stop decision ----
    if (t > 1) {
      const int g = t - 2;
      if (wid == 0 && lane < 2) {           // wave 0: neighbor red flags
        int nb = (lane == 0) ? (bid - 1) : (bid + 1);
        if (nb >= 0 && nb < NBLK) {
          while (cloadu(&ctrl[(276u + (unsigned)nb) * 16u])
                 < (unsigned long long)(t - 1))
            __builtin_amdgcn_s_sleep(1);
        }
      }
      if (g >= 1 && wid == 1 && lane < 16) { // wave 1: dv ring poll
        const int r = g & 7;
        const unsigned n = ((unsigned)g + 7u) >> 3;
        const unsigned long long t64 =
            ((unsigned long long)NBLK * n) << 44;
        unsigned long long v;
        for (;;) {
          v = cloadu(&ctrl[((unsigned)r * 16u + (unsigned)lane) * 16u]);
          v += __shfl_xor(v, 1, 64);  v += __shfl_xor(v, 2, 64);
          v += __shfl_xor(v, 4, 64);  v += __shfl_xor(v, 8, 64);
          if (v >= t64) break;
          __builtin_amdgcn_s_sleep(1);
        }
        if (lane == 0) {
          unsigned long long cum = v & MASK44;
          sh_dv = (double)(cum - prevs[r]) * (1.0 / 1048576.0);
          prevs[r] = cum;
        }
      }
      __syncthreads();
      if (g >= 1) {
        double dvg = sh_dv;
        if (!((dvg >= 0.05) && (g <= 500))) { itout = g; dvout = dvg; break; }
      }
    }

    double acc = 0.0;
    // ================= BLACK sweep (cross: red values, t-1) =============
    {
      const float* __restrict__ rdm = prold + offRm;
      const float* __restrict__ rdp = prold + offRp;
      float* __restrict__ wm = pbcur + offPm;
      float* __restrict__ wp = pbcur + offPp;
      for (int p = tid; p < cntB; p += NTHR) {
        const int o = (int)lsB[p];
        const unsigned u = auxB[p];
        const unsigned cm = u & 0xFFFFu, cp = u >> 16;
        double fzm = (cm & 0x8000u) ? (double)(cm & 1u)
                                    : (double)cloadf(&rdm[cm]);
        double fzp = (cp & 0x8000u) ? (double)(cp & 1u)
                                    : (double)cloadf(&rdp[cp]);
        double xi = P1[o];
        double nb = ((((P1[o - 1] + P1[o + 1]) + P1[o - NJK]) + P1[o + NJK])
                    + fzm) + fzp;
        double adj = (WOPT * (nb - 6.0 * xi)) / 6.0;
        double v = xi + adj;
        P1[o] = v;
        if (!(cm & 0x8000u)) cstoref(&wm[cm], (float)v);
        if (!(cp & 0x8000u)) cstoref(&wp[cp], (float)v);
        acc += fabs(adj);
      }
    }
    __syncthreads();                       // LDS visible + publishes drained
    if (tid == 0)
      cstoreu(&ctrl[(144u + (unsigned)bid) * 16u], (unsigned long long)t);
    if (tid < 2) {                         // wait neighbors' black publish
      int nb = (tid == 0) ? (bid - 1) : (bid + 1);
      if (nb >= 0 && nb < NBLK) {
        while (cloadu(&ctrl[(144u + (unsigned)nb) * 16u])
               < (unsigned long long)t)
          __builtin_amdgcn_s_sleep(1);
      }
    }
    __syncthreads();

    // ================= RED sweep (cross: black values, t) ===============
    {
      const float* __restrict__ rdm = pbcur + offRm;
      const float* __restrict__ rdp = pbcur + offRp;
      float* __restrict__ wm = prcur + offPm;
      float* __restrict__ wp = prcur + offPp;
      for (int p = tid; p < cntR; p += NTHR) {
        const int o = (int)lsR[p];
        const unsigned u = auxR[p];
        const unsigned cm = u & 0xFFFFu, cp = u >> 16;
        double fzm = (cm & 0x8000u) ? (double)(cm & 1u)
                                    : (double)cloadf(&rdm[cm]);
        double fzp = (cp & 0x8000u) ? (double)(cp & 1u)
                                    : (double)cloadf(&rdp[cp]);
        double xi = P1[o];
        double nb = ((((P1[o - 1] + P1[o + 1]) + P1[o - NJK]) + P1[o + NJK])
                    + fzm) + fzp;
        double adj = (WOPT * (nb - 6.0 * xi)) / 6.0;
        double v = xi + adj;
        P1[o] = v;
        if (!(cm & 0x8000u)) cstoref(&wm[cm], (float)v);
        if (!(cp & 0x8000u)) cstoref(&wp[cp], (float)v);
        acc += fabs(adj);
      }
    }

    // ---- block dv reduce (fixed order) + flag + ring post ----
    double a = acc;
    #pragma unroll
    for (int m = 32; m >= 1; m >>= 1) a += __shfl_xor(a, m, 64);
    if (lane == 0) redw[wid] = a;
    __syncthreads();                       // drains red publish; redw ready
    if (tid == 0) {
      double s = redw[0];
      #pragma unroll
      for (int w = 1; w < NW; ++w) s += redw[w];
      cstoreu(&ctrl[(276u + (unsigned)bid) * 16u], (unsigned long long)t);
      __hip_atomic_fetch_add(
          &ctrl[(((unsigned)t & 7u) * 16u + (unsigned)(bid & 15)) * 16u],
          CNT1 + (unsigned long long)(s * 1048576.0 + 0.5),
          __ATOMIC_RELAXED, __HIP_MEMORY_SCOPE_AGENT);
    }
  }

  // ---- epilogue: lap straight from LDS (crop pad), + iters + dv ----
  {
    const int vb = (z >= 66) ? 1 : 0;
    const int pz = z - 66 * vb;
    if (pz >= 1 && pz <= 64) {
      float* ob = out + ((size_t)vb * 64 + (pz - 1)) * 4096;
      for (int t2 = tid; t2 < 4096; t2 += NTHR) {
        int jj = t2 >> 6, kk = t2 & 63;
        ob[t2] = (float)P1[NJK * (jj + 1) + (kk + 1)];
      }
    }
    if (z == 0 && tid == 0) {
      out[NOUT]     = (float)itout;
      out[NOUT + 1] = (float)dvout;
    }
  }
}

extern "C" void kernel_launch(void* const* d_in, const int* in_sizes, int n_in,
                              void* d_out, int out_size, void* d_ws, size_t ws_size,
                              hipStream_t stream) {
  const float* img = (const float*)d_in[0];
  float* out = (float*)d_out;
  const size_t CH_ELEMS = (size_t)NIF * 2 * SLOT;
  float* pb0 = (float*)d_ws;
  float* pb1 = pb0 + CH_ELEMS;
  float* pr0 = pb1 + CH_ELEMS;
  float* pr1 = pr0 + CH_ELEMS;
  unsigned long long* ctrl = (unsigned long long*)(pr1 + CH_ELEMS);

  sor_init_ctrl<<<1, 256, 0, stream>>>(ctrl);
  sor_main<<<NBLK, NTHR, 0, stream>>>(img, pb0, pb1, pr0, pr1, ctrl, out);
}

// Round 20
// 559.722 us; speedup vs baseline: 1.3026x; 1.0886x over previous
//
#include <hip/hip_runtime.h>
#include <cstdint>

// ---------------------------------------------------------------------------
// Red-black SOR Laplace solver, persistent kernel. Round 20 = round 14 with
// the MID-ITERATION black exchange deleted via halo-black recomputation.
// Block z owns plane z (f64 in LDS). It also locally advances XB values =
// black states of planes z-1/z+1 at exactly the positions its own red
// voxels read (cross sets, ~140/dir). XB update inputs: red(t-1) packed
// channels of z-1/z+1 (in-plane) and z-2/z+2 (far) + own P1[o] — all
// available at iteration start, since black voxels never neighbor black.
// Per iteration: ONE wait (red flags z+-1,z+-2 >= t-1, 4 lanes, || dv-ring
// poll) -> black own sweep (r14's uniform packed reads) + XB updates ->
// syncthreads -> red own sweep (crosses = XB from LDS; inline publish) ->
// dv reduce + flag + ring. pr channels parity-2 (safety: writer at t+2
// waited flags >= t+1 of all its readers). Depth-8 dv ring, lagged exact
// stop at g=t-2 -> uniform break; reports iters=149 and dv(149) exactly.
// Numerics: black sweep bit-identical to r14; red crosses perturbed ~1e-7
// (f64-of-f32-inputs), far below the r10-proven tolerance -> iters=149.
// ---------------------------------------------------------------------------

#define NBLK 132
#define NTHR 1024
#define NW   (NTHR / 64)

constexpr int NJK   = 66;
constexpr int PLANE = 66 * 66;          // 4356
constexpr int HPL   = PLANE / 2;        // 2178 packed entries per half
constexpr int NI    = 132;
constexpr int CAPL  = 2048;             // max gm per color per plane
constexpr int CAPH  = 768;              // halo cross-set cap (mean ~136)
constexpr int NOUT  = 2 * 64 * 64 * 64; // 524288
// ctrl 128B lines: [0..127] dv rings 0..7 (16 lines each); [128..143]
// startup barrier; [276..407] red flags (276+b).
constexpr int CTRL_U64 = 408 * 16;
constexpr unsigned long long CNT1   = 1ull << 44;
constexpr unsigned long long MASK44 = CNT1 - 1ull;

__global__ void sor_init_ctrl(unsigned long long* ctrl) {
  for (int i = threadIdx.x; i < CTRL_U64; i += blockDim.x) ctrl[i] = 0ull;
}

__device__ __forceinline__ float cloadf(const float* p) {
  return __hip_atomic_load(p, __ATOMIC_RELAXED, __HIP_MEMORY_SCOPE_AGENT);
}
__device__ __forceinline__ void cstoref(float* p, float v) {
  __hip_atomic_store(p, v, __ATOMIC_RELAXED, __HIP_MEMORY_SCOPE_AGENT);
}
__device__ __forceinline__ unsigned long long cloadu(const unsigned long long* p) {
  return __hip_atomic_load(p, __ATOMIC_RELAXED, __HIP_MEMORY_SCOPE_AGENT);
}
__device__ __forceinline__ void cstoreu(unsigned long long* p, unsigned long long v) {
  __hip_atomic_store(p, v, __ATOMIC_RELAXED, __HIP_MEMORY_SCOPE_AGENT);
}

// padded flat coords -> original image flat index, or -1 if pad voxel
__device__ __forceinline__ int pad_label_idx(int ii, int jj, int kk) {
  int b  = (ii >= 66) ? 1 : 0;
  int pz = ii - 66 * b;
  if (pz < 1 || pz > 64 || jj < 1 || jj > 64 || kk < 1 || kk > 64) return -1;
  return ((b * 64 + (pz - 1)) * 64 + (jj - 1)) * 64 + (kk - 1);
}

__global__ __launch_bounds__(NTHR, 1)
void sor_main(const float* __restrict__ img,
              float* __restrict__ pr0, float* __restrict__ pr1,
              unsigned long long* __restrict__ ctrl,
              float* __restrict__ out) {
  __shared__ double P1[PLANE];                 // own plane, f64
  __shared__ double XBm[CAPH], XBp[CAPH];      // halo-black states z-1 / z+1
  __shared__ unsigned short hm[CAPH], hp[CAPH];
  __shared__ unsigned short tmpm[PLANE], tmpp[PLANE];  // o -> halo rank
  __shared__ unsigned lsB[CAPL], lsR[CAPL];    // o | (c<<16)
  __shared__ unsigned auxR[CAPL];              // im | (ip<<16)
  __shared__ unsigned wsum[NW], woff[NW];
  __shared__ unsigned tot;
  __shared__ double redw[NW];
  __shared__ unsigned long long prevs[8];
  __shared__ double sh_dv;

  const int tid = threadIdx.x, bid = blockIdx.x;
  const int lane = tid & 63, wid = tid >> 6;
  const int z = bid;

  // ---- init own plane + XB + rank maps ----
  for (int o = tid; o < PLANE; o += NTHR) {
    int j = o / NJK, k = o - j * NJK;
    int li = pad_label_idx(z, j, k);
    float L = (li >= 0) ? img[li] : 0.0f;
    P1[o] = (L == 3.0f) ? 1.0 : 0.0;
    tmpm[o] = 0xFFFFu; tmpp[o] = 0xFFFFu;
  }
  for (int i = tid; i < CAPH; i += NTHR) { XBm[i] = 0.0; XBp[i] = 0.0; }
  if (tid < 8) prevs[tid] = 0ull;
  __syncthreads();

  const int CH = (PLANE + NTHR - 1) / NTHR;
  int cntB = 0, cntR = 0, nHm = 0, nHp = 0;

  // ---- pass 0: black list (o | c<<16) ----
  {
    int c0 = tid * CH, c1 = (c0 + CH < PLANE) ? (c0 + CH) : PLANE;
    unsigned cnt = 0;
    for (int o = c0; o < c1; ++o) {
      int j = o / NJK, k = o - j * NJK;
      if (((z + j + k) & 1) != 0) continue;
      int li = pad_label_idx(z, j, k);
      if (((li >= 0) ? img[li] : 0.0f) == 1.0f) cnt++;
    }
    unsigned incl = cnt;
    #pragma unroll
    for (int m = 1; m < 64; m <<= 1) {
      unsigned t = __shfl_up(incl, m, 64);
      if (lane >= m) incl += t;
    }
    __syncthreads();
    if (lane == 63) wsum[wid] = incl;
    __syncthreads();
    if (tid == 0) {
      unsigned a = 0;
      for (int w = 0; w < NW; ++w) { unsigned c = wsum[w]; woff[w] = a; a += c; }
      tot = a;
    }
    __syncthreads();
    unsigned p = (incl - cnt) + woff[wid];
    for (int o = c0; o < c1; ++o) {
      int j = o / NJK, k = o - j * NJK;
      if (((z + j + k) & 1) != 0) continue;
      int li = pad_label_idx(z, j, k);
      if (((li >= 0) ? img[li] : 0.0f) == 1.0f)
        lsB[p++] = (unsigned)o | ((unsigned)(o >> 1) << 16);
    }
    __syncthreads();
    cntB = (int)tot;
    __syncthreads();
  }

  // ---- passes 1/2: halo cross lists per direction (red-in-z, gm both) ----
  for (int dir = 0; dir < 2; ++dir) {
    const int zx = (dir == 0) ? (z - 1) : (z + 1);
    unsigned short* hl  = (dir == 0) ? hm : hp;
    unsigned short* tmp = (dir == 0) ? tmpm : tmpp;
    int c0 = tid * CH, c1 = (c0 + CH < PLANE) ? (c0 + CH) : PLANE;
    unsigned cnt = 0;
    for (int o = c0; o < c1; ++o) {
      int j = o / NJK, k = o - j * NJK;
      if (((z + j + k) & 1) != 1) continue;
      int li = pad_label_idx(z, j, k);
      if (((li >= 0) ? img[li] : 0.0f) != 1.0f) continue;
      int lx = pad_label_idx(zx, j, k);
      if (((lx >= 0) ? img[lx] : 0.0f) == 1.0f) cnt++;
    }
    unsigned incl = cnt;
    #pragma unroll
    for (int m = 1; m < 64; m <<= 1) {
      unsigned t = __shfl_up(incl, m, 64);
      if (lane >= m) incl += t;
    }
    __syncthreads();
    if (lane == 63) wsum[wid] = incl;
    __syncthreads();
    if (tid == 0) {
      unsigned a = 0;
      for (int w = 0; w < NW; ++w) { unsigned c = wsum[w]; woff[w] = a; a += c; }
      tot = a;
    }
    __syncthreads();
    unsigned p = (incl - cnt) + woff[wid];
    for (int o = c0; o < c1; ++o) {
      int j = o / NJK, k = o - j * NJK;
      if (((z + j + k) & 1) != 1) continue;
      int li = pad_label_idx(z, j, k);
      if (((li >= 0) ? img[li] : 0.0f) != 1.0f) continue;
      int lx = pad_label_idx(zx, j, k);
      if (((lx >= 0) ? img[lx] : 0.0f) == 1.0f) {
        hl[p] = (unsigned short)o;
        tmp[o] = (unsigned short)p;
        p++;
      }
    }
    __syncthreads();
    if (dir == 0) nHm = (int)tot; else nHp = (int)tot;
    __syncthreads();
  }

  // ---- pass 3: red list + aux codes ----
  {
    int c0 = tid * CH, c1 = (c0 + CH < PLANE) ? (c0 + CH) : PLANE;
    unsigned cnt = 0;
    for (int o = c0; o < c1; ++o) {
      int j = o / NJK, k = o - j * NJK;
      if (((z + j + k) & 1) != 1) continue;
      int li = pad_label_idx(z, j, k);
      if (((li >= 0) ? img[li] : 0.0f) == 1.0f) cnt++;
    }
    unsigned incl = cnt;
    #pragma unroll
    for (int m = 1; m < 64; m <<= 1) {
      unsigned t = __shfl_up(incl, m, 64);
      if (lane >= m) incl += t;
    }
    __syncthreads();
    if (lane == 63) wsum[wid] = incl;
    __syncthreads();
    if (tid == 0) {
      unsigned a = 0;
      for (int w = 0; w < NW; ++w) { unsigned c = wsum[w]; woff[w] = a; a += c; }
      tot = a;
    }
    __syncthreads();
    unsigned p = (incl - cnt) + woff[wid];
    for (int o = c0; o < c1; ++o) {
      int j = o / NJK, k = o - j * NJK;
      if (((z + j + k) & 1) != 1) continue;
      int li = pad_label_idx(z, j, k);
      if (((li >= 0) ? img[li] : 0.0f) != 1.0f) continue;
      int lm = pad_label_idx(z - 1, j, k);
      float Lm = (lm >= 0) ? img[lm] : 0.0f;
      int lp = pad_label_idx(z + 1, j, k);
      float Lp = (lp >= 0) ? img[lp] : 0.0f;
      unsigned im = (tmpm[o] != 0xFFFFu) ? (unsigned)tmpm[o]
                                         : (0x8000u | (Lm == 3.0f ? 1u : 0u));
      unsigned ip = (tmpp[o] != 0xFFFFu) ? (unsigned)tmpp[o]
                                         : (0x8000u | (Lp == 3.0f ? 1u : 0u));
      lsR[p]  = (unsigned)o | ((unsigned)(o >> 1) << 16);
      auxR[p] = im | (ip << 16);
      p++;
    }
    __syncthreads();
    cntR = (int)tot;
    __syncthreads();
  }

  // ---- prefill BOTH pr parities with the full red half (consts + init) ----
  for (int c = tid; c < HPL; c += NTHR) {
    int j = c / 33, m = c - 33 * j;
    int k = (m << 1) + ((z + j + 1) & 1);     // red positions of plane z
    float v = (float)P1[NJK * j + k];
    cstoref(&pr0[(size_t)z * HPL + c], v);
    cstoref(&pr1[(size_t)z * HPL + c], v);
  }
  __syncthreads();                         // drain prefill
  // ---- startup barrier (count-only, 16 lines) ----
  if (tid == 0)
    __hip_atomic_fetch_add(&ctrl[(128u + (unsigned)(bid & 15)) * 16u], 1ull,
                           __ATOMIC_RELAXED, __HIP_MEMORY_SCOPE_AGENT);
  if (tid < 16) {
    for (;;) {
      unsigned long long v = cloadu(&ctrl[(128u + (unsigned)tid) * 16u]);
      v += __shfl_xor(v, 1, 64);  v += __shfl_xor(v, 2, 64);
      v += __shfl_xor(v, 4, 64);  v += __shfl_xor(v, 8, 64);
      if (v >= (unsigned long long)NBLK) break;
      __builtin_amdgcn_s_sleep(1);
    }
  }
  __syncthreads();

  const double WOPT = 2.0 / (1.0 + 3.14159265358979323846 / 66.0);
  const int zmc  = (z >= 1) ? (z - 1) : 0;
  const int zpc  = (z <= NI - 2) ? (z + 1) : (NI - 1);
  const int zm2c = (z >= 2) ? (z - 2) : 0;
  const int zp2c = (z <= NI - 3) ? (z + 2) : (NI - 1);

  int itout = 0;
  double dvout = 0.0;

  for (int t = 1; t <= 555; ++t) {
    const float* __restrict__ prold = (t & 1) ? pr0 : pr1;  // pr[(t-1)&1]
    float* __restrict__ prcur       = (t & 1) ? pr1 : pr0;  // pr[t&1]

    // ---- start-of-iter: flag waits (z+-1, z+-2) || ring poll + stop ----
    if (t > 1) {
      const int g = t - 2;
      if (wid == 0 && lane < 4) {
        int d = (lane < 2) ? 1 : 2;
        int nb = z + ((lane & 1) ? d : -d);
        if (nb >= 0 && nb < NBLK) {
          while (cloadu(&ctrl[(276u + (unsigned)nb) * 16u])
                 < (unsigned long long)(t - 1))
            __builtin_amdgcn_s_sleep(1);
        }
      }
      if (g >= 1 && wid == 1 && lane < 16) {
        const int r = g & 7;
        const unsigned n = ((unsigned)g + 7u) >> 3;
        const unsigned long long t64 =
            ((unsigned long long)NBLK * n) << 44;
        unsigned long long v;
        for (;;) {
          v = cloadu(&ctrl[((unsigned)r * 16u + (unsigned)lane) * 16u]);
          v += __shfl_xor(v, 1, 64);  v += __shfl_xor(v, 2, 64);
          v += __shfl_xor(v, 4, 64);  v += __shfl_xor(v, 8, 64);
          if (v >= t64) break;
          __builtin_amdgcn_s_sleep(1);
        }
        if (lane == 0) {
          unsigned long long cum = v & MASK44;
          sh_dv = (double)(cum - prevs[r]) * (1.0 / 1048576.0);
          prevs[r] = cum;
        }
      }
      __syncthreads();
      if (g >= 1) {
        double dvg = sh_dv;
        if (!((dvg >= 0.05) && (g <= 500))) { itout = g; dvout = dvg; break; }
      }
    }

    double acc = 0.0;
    // ====== BLACK own sweep (uniform packed cross reads, r14-exact) ======
    {
      const float* __restrict__ rm = prold + (size_t)zmc * HPL;
      const float* __restrict__ rp = prold + (size_t)zpc * HPL;
      for (int p = tid; p < cntB; p += NTHR) {
        const unsigned u = lsB[p];
        const int o = (int)(u & 0xFFFFu);
        const int c = (int)(u >> 16);
        double fzm = (double)cloadf(&rm[c]);
        double fzp = (double)cloadf(&rp[c]);
        double xi = P1[o];
        double nb = ((((P1[o - 1] + P1[o + 1]) + P1[o - NJK]) + P1[o + NJK])
                    + fzm) + fzp;
        double adj = (WOPT * (nb - 6.0 * xi)) / 6.0;
        P1[o] = xi + adj;
        acc += fabs(adj);
      }
    }
    // ====== halo-black updates (no dv; disjoint from black sweep) ======
    {
      const float* __restrict__ chm  = prold + (size_t)zmc * HPL;
      const float* __restrict__ chm2 = prold + (size_t)zm2c * HPL;
      for (int i = tid; i < nHm; i += NTHR) {
        const int o = (int)hm[i];
        const int c = o >> 1;
        double x = XBm[i];
        double nb = (((((double)cloadf(&chm[(o - 1) >> 1])
                      + (double)cloadf(&chm[(o + 1) >> 1]))
                      + (double)cloadf(&chm[c - 33]))
                      + (double)cloadf(&chm[c + 33]))
                      + (double)cloadf(&chm2[c])) + P1[o];
        XBm[i] = x + (WOPT * (nb - 6.0 * x)) / 6.0;
      }
      const float* __restrict__ chp  = prold + (size_t)zpc * HPL;
      const float* __restrict__ chp2 = prold + (size_t)zp2c * HPL;
      for (int i = tid; i < nHp; i += NTHR) {
        const int o = (int)hp[i];
        const int c = o >> 1;
        double x = XBp[i];
        double nb = (((((double)cloadf(&chp[(o - 1) >> 1])
                      + (double)cloadf(&chp[(o + 1) >> 1]))
                      + (double)cloadf(&chp[c - 33]))
                      + (double)cloadf(&chp[c + 33]))
                      + P1[o]) + (double)cloadf(&chp2[c]);
        XBp[i] = x + (WOPT * (nb - 6.0 * x)) / 6.0;
      }
    }
    __syncthreads();   // black P1 + XB visible

    // ====== RED own sweep: crosses from XB (LDS); inline publish ======
    {
      float* __restrict__ wpub = prcur + (size_t)z * HPL;
      for (int p = tid; p < cntR; p += NTHR) {
        const unsigned u = lsR[p];
        const int o = (int)(u & 0xFFFFu);
        const int c = (int)(u >> 16);
        const unsigned a2 = auxR[p];
        const unsigned im = a2 & 0xFFFFu, ip = a2 >> 16;
        double fzm = (im & 0x8000u) ? (double)(im & 1u) : XBm[im];
        double fzp = (ip & 0x8000u) ? (double)(ip & 1u) : XBp[ip];
        double xi = P1[o];
        double nb = ((((P1[o - 1] + P1[o + 1]) + P1[o - NJK]) + P1[o + NJK])
                    + fzm) + fzp;
        double adj = (WOPT * (nb - 6.0 * xi)) / 6.0;
        double v = xi + adj;
        P1[o] = v;
        cstoref(&wpub[c], (float)v);
        acc += fabs(adj);
      }
    }

    // ---- dv reduce (fixed order) + red flag + ring post ----
    double a = acc;
    #pragma unroll
    for (int m = 32; m >= 1; m >>= 1) a += __shfl_xor(a, m, 64);
    if (lane == 0) redw[wid] = a;
    __syncthreads();                       // drains publishes; redw ready
    if (tid == 0) {
      double s = redw[0];
      #pragma unroll
      for (int w = 1; w < NW; ++w) s += redw[w];
      cstoreu(&ctrl[(276u + (unsigned)bid) * 16u], (unsigned long long)t);
      __hip_atomic_fetch_add(
          &ctrl[(((unsigned)t & 7u) * 16u + (unsigned)(bid & 15)) * 16u],
          CNT1 + (unsigned long long)(s * 1048576.0 + 0.5),
          __ATOMIC_RELAXED, __HIP_MEMORY_SCOPE_AGENT);
    }
  }

  // ---- epilogue: lap straight from LDS (crop pad), + iters + dv ----
  {
    const int vb = (z >= 66) ? 1 : 0;
    const int pz = z - 66 * vb;
    if (pz >= 1 && pz <= 64) {
      float* ob = out + ((size_t)vb * 64 + (pz - 1)) * 4096;
      for (int t2 = tid; t2 < 4096; t2 += NTHR) {
        int jj = t2 >> 6, kk = t2 & 63;
        ob[t2] = (float)P1[NJK * (jj + 1) + (kk + 1)];
      }
    }
    if (z == 0 && tid == 0) {
      out[NOUT]     = (float)itout;
      out[NOUT + 1] = (float)dvout;
    }
  }
}

extern "C" void kernel_launch(void* const* d_in, const int* in_sizes, int n_in,
                              void* d_out, int out_size, void* d_ws, size_t ws_size,
                              hipStream_t stream) {
  const float* img = (const float*)d_in[0];
  float* out = (float*)d_out;
  float* pr0 = (float*)d_ws;
  float* pr1 = pr0 + (size_t)NI * HPL;
  unsigned long long* ctrl = (unsigned long long*)(pr1 + (size_t)NI * HPL);

  sor_init_ctrl<<<1, 256, 0, stream>>>(ctrl);
  sor_main<<<NBLK, NTHR, 0, stream>>>(img, pr0, pr1, ctrl, out);
}

// Round 21
// 527.129 us; speedup vs baseline: 1.3831x; 1.0618x over previous
//
#include <hip/hip_runtime.h>
#include <cstdint>

// ---------------------------------------------------------------------------
// Red-black SOR Laplace solver, persistent kernel. Round 21 = round 20
// (single flag-sync per iteration via halo-black recomputation) + LDS
// STAGING of the neighbor channels: prold[z-1], prold[z+1] full packed red
// halves (coalesced burst, registers-then-LDS for MLP) and the ~140/dir far
// entries of prold[z-2], prold[z+2] are staged into LDS right after the
// flag wait. Black sweep, halo-XB updates, and red sweep then read LDS
// only — r20's ~1400 scattered sc1 LLC transactions are gone.
// Per iteration: ONE wait (red flags z+-1,z+-2 >= t-1, || dv-ring poll) ->
// stage burst -> sync -> black own sweep + XB updates (LDS) -> sync ->
// red own sweep (XB in LDS) + inline publish -> dv reduce + flag + ring.
// Staged values are the identical f32 bits r20 loaded directly; same op
// order -> same trajectory (r20 passed, iters=149). Depth-8 dv ring,
// lagged exact stop at g=t-2; reports iters=149 and dv(149) exactly.
// ---------------------------------------------------------------------------

#define NBLK 132
#define NTHR 1024
#define NW   (NTHR / 64)

constexpr int NJK   = 66;
constexpr int PLANE = 66 * 66;          // 4356
constexpr int HPL   = PLANE / 2;        // 2178 packed entries per half
constexpr int NI    = 132;
constexpr int CAPL  = 2048;             // max gm per color per plane
constexpr int CAPH  = 768;              // halo cross-set cap (mean ~136)
constexpr int NOUT  = 2 * 64 * 64 * 64; // 524288
// ctrl 128B lines: [0..127] dv rings 0..7 (16 lines each); [128..143]
// startup barrier; [276..407] red flags (276+b).
constexpr int CTRL_U64 = 408 * 16;
constexpr unsigned long long CNT1   = 1ull << 44;
constexpr unsigned long long MASK44 = CNT1 - 1ull;

__global__ void sor_init_ctrl(unsigned long long* ctrl) {
  for (int i = threadIdx.x; i < CTRL_U64; i += blockDim.x) ctrl[i] = 0ull;
}

__device__ __forceinline__ float cloadf(const float* p) {
  return __hip_atomic_load(p, __ATOMIC_RELAXED, __HIP_MEMORY_SCOPE_AGENT);
}
__device__ __forceinline__ void cstoref(float* p, float v) {
  __hip_atomic_store(p, v, __ATOMIC_RELAXED, __HIP_MEMORY_SCOPE_AGENT);
}
__device__ __forceinline__ unsigned long long cloadu(const unsigned long long* p) {
  return __hip_atomic_load(p, __ATOMIC_RELAXED, __HIP_MEMORY_SCOPE_AGENT);
}
__device__ __forceinline__ void cstoreu(unsigned long long* p, unsigned long long v) {
  __hip_atomic_store(p, v, __ATOMIC_RELAXED, __HIP_MEMORY_SCOPE_AGENT);
}

// padded flat coords -> original image flat index, or -1 if pad voxel
__device__ __forceinline__ int pad_label_idx(int ii, int jj, int kk) {
  int b  = (ii >= 66) ? 1 : 0;
  int pz = ii - 66 * b;
  if (pz < 1 || pz > 64 || jj < 1 || jj > 64 || kk < 1 || kk > 64) return -1;
  return ((b * 64 + (pz - 1)) * 64 + (jj - 1)) * 64 + (kk - 1);
}

__global__ __launch_bounds__(NTHR, 1)
void sor_main(const float* __restrict__ img,
              float* __restrict__ pr0, float* __restrict__ pr1,
              unsigned long long* __restrict__ ctrl,
              float* __restrict__ out) {
  __shared__ double P1[PLANE];                 // own plane, f64
  __shared__ double XBm[CAPH], XBp[CAPH];      // halo-black states z-1 / z+1
  __shared__ unsigned short hm[CAPH], hp[CAPH];
  __shared__ unsigned short tmpm[PLANE], tmpp[PLANE];  // o -> halo rank
  __shared__ unsigned lsB[CAPL], lsR[CAPL];    // o | (c<<16)
  __shared__ unsigned auxR[CAPL];              // im | (ip<<16)
  __shared__ float CM[HPL], CP[HPL];           // staged red halves z-1 / z+1
  __shared__ float FM[CAPH], FP[CAPH];         // staged far entries z-2 / z+2
  __shared__ unsigned wsum[NW], woff[NW];
  __shared__ unsigned tot;
  __shared__ double redw[NW];
  __shared__ unsigned long long prevs[8];
  __shared__ double sh_dv;

  const int tid = threadIdx.x, bid = blockIdx.x;
  const int lane = tid & 63, wid = tid >> 6;
  const int z = bid;

  // ---- init own plane + XB + rank maps ----
  for (int o = tid; o < PLANE; o += NTHR) {
    int j = o / NJK, k = o - j * NJK;
    int li = pad_label_idx(z, j, k);
    float L = (li >= 0) ? img[li] : 0.0f;
    P1[o] = (L == 3.0f) ? 1.0 : 0.0;
    tmpm[o] = 0xFFFFu; tmpp[o] = 0xFFFFu;
  }
  for (int i = tid; i < CAPH; i += NTHR) { XBm[i] = 0.0; XBp[i] = 0.0; }
  if (tid < 8) prevs[tid] = 0ull;
  __syncthreads();

  const int CH = (PLANE + NTHR - 1) / NTHR;
  int cntB = 0, cntR = 0, nHm = 0, nHp = 0;

  // ---- pass 0: black list (o | c<<16) ----
  {
    int c0 = tid * CH, c1 = (c0 + CH < PLANE) ? (c0 + CH) : PLANE;
    unsigned cnt = 0;
    for (int o = c0; o < c1; ++o) {
      int j = o / NJK, k = o - j * NJK;
      if (((z + j + k) & 1) != 0) continue;
      int li = pad_label_idx(z, j, k);
      if (((li >= 0) ? img[li] : 0.0f) == 1.0f) cnt++;
    }
    unsigned incl = cnt;
    #pragma unroll
    for (int m = 1; m < 64; m <<= 1) {
      unsigned t = __shfl_up(incl, m, 64);
      if (lane >= m) incl += t;
    }
    __syncthreads();
    if (lane == 63) wsum[wid] = incl;
    __syncthreads();
    if (tid == 0) {
      unsigned a = 0;
      for (int w = 0; w < NW; ++w) { unsigned c = wsum[w]; woff[w] = a; a += c; }
      tot = a;
    }
    __syncthreads();
    unsigned p = (incl - cnt) + woff[wid];
    for (int o = c0; o < c1; ++o) {
      int j = o / NJK, k = o - j * NJK;
      if (((z + j + k) & 1) != 0) continue;
      int li = pad_label_idx(z, j, k);
      if (((li >= 0) ? img[li] : 0.0f) == 1.0f)
        lsB[p++] = (unsigned)o | ((unsigned)(o >> 1) << 16);
    }
    __syncthreads();
    cntB = (int)tot;
    __syncthreads();
  }

  // ---- passes 1/2: halo cross lists per direction (red-in-z, gm both) ----
  for (int dir = 0; dir < 2; ++dir) {
    const int zx = (dir == 0) ? (z - 1) : (z + 1);
    unsigned short* hl  = (dir == 0) ? hm : hp;
    unsigned short* tmp = (dir == 0) ? tmpm : tmpp;
    int c0 = tid * CH, c1 = (c0 + CH < PLANE) ? (c0 + CH) : PLANE;
    unsigned cnt = 0;
    for (int o = c0; o < c1; ++o) {
      int j = o / NJK, k = o - j * NJK;
      if (((z + j + k) & 1) != 1) continue;
      int li = pad_label_idx(z, j, k);
      if (((li >= 0) ? img[li] : 0.0f) != 1.0f) continue;
      int lx = pad_label_idx(zx, j, k);
      if (((lx >= 0) ? img[lx] : 0.0f) == 1.0f) cnt++;
    }
    unsigned incl = cnt;
    #pragma unroll
    for (int m = 1; m < 64; m <<= 1) {
      unsigned t = __shfl_up(incl, m, 64);
      if (lane >= m) incl += t;
    }
    __syncthreads();
    if (lane == 63) wsum[wid] = incl;
    __syncthreads();
    if (tid == 0) {
      unsigned a = 0;
      for (int w = 0; w < NW; ++w) { unsigned c = wsum[w]; woff[w] = a; a += c; }
      tot = a;
    }
    __syncthreads();
    unsigned p = (incl - cnt) + woff[wid];
    for (int o = c0; o < c1; ++o) {
      int j = o / NJK, k = o - j * NJK;
      if (((z + j + k) & 1) != 1) continue;
      int li = pad_label_idx(z, j, k);
      if (((li >= 0) ? img[li] : 0.0f) != 1.0f) continue;
      int lx = pad_label_idx(zx, j, k);
      if (((lx >= 0) ? img[lx] : 0.0f) == 1.0f) {
        hl[p] = (unsigned short)o;
        tmp[o] = (unsigned short)p;
        p++;
      }
    }
    __syncthreads();
    if (dir == 0) nHm = (int)tot; else nHp = (int)tot;
    __syncthreads();
  }

  // ---- pass 3: red list + aux codes ----
  {
    int c0 = tid * CH, c1 = (c0 + CH < PLANE) ? (c0 + CH) : PLANE;
    unsigned cnt = 0;
    for (int o = c0; o < c1; ++o) {
      int j = o / NJK, k = o - j * NJK;
      if (((z + j + k) & 1) != 1) continue;
      int li = pad_label_idx(z, j, k);
      if (((li >= 0) ? img[li] : 0.0f) == 1.0f) cnt++;
    }
    unsigned incl = cnt;
    #pragma unroll
    for (int m = 1; m < 64; m <<= 1) {
      unsigned t = __shfl_up(incl, m, 64);
      if (lane >= m) incl += t;
    }
    __syncthreads();
    if (lane == 63) wsum[wid] = incl;
    __syncthreads();
    if (tid == 0) {
      unsigned a = 0;
      for (int w = 0; w < NW; ++w) { unsigned c = wsum[w]; woff[w] = a; a += c; }
      tot = a;
    }
    __syncthreads();
    unsigned p = (incl - cnt) + woff[wid];
    for (int o = c0; o < c1; ++o) {
      int j = o / NJK, k = o - j * NJK;
      if (((z + j + k) & 1) != 1) continue;
      int li = pad_label_idx(z, j, k);
      if (((li >= 0) ? img[li] : 0.0f) != 1.0f) continue;
      int lm = pad_label_idx(z - 1, j, k);
      float Lm = (lm >= 0) ? img[lm] : 0.0f;
      int lp = pad_label_idx(z + 1, j, k);
      float Lp = (lp >= 0) ? img[lp] : 0.0f;
      unsigned im = (tmpm[o] != 0xFFFFu) ? (unsigned)tmpm[o]
                                         : (0x8000u | (Lm == 3.0f ? 1u : 0u));
      unsigned ip = (tmpp[o] != 0xFFFFu) ? (unsigned)tmpp[o]
                                         : (0x8000u | (Lp == 3.0f ? 1u : 0u));
      lsR[p]  = (unsigned)o | ((unsigned)(o >> 1) << 16);
      auxR[p] = im | (ip << 16);
      p++;
    }
    __syncthreads();
    cntR = (int)tot;
    __syncthreads();
  }

  // ---- prefill BOTH pr parities with the full red half (consts + init) ----
  for (int c = tid; c < HPL; c += NTHR) {
    int j = c / 33, m = c - 33 * j;
    int k = (m << 1) + ((z + j + 1) & 1);     // red positions of plane z
    float v = (float)P1[NJK * j + k];
    cstoref(&pr0[(size_t)z * HPL + c], v);
    cstoref(&pr1[(size_t)z * HPL + c], v);
  }
  __syncthreads();                         // drain prefill
  // ---- startup barrier (count-only, 16 lines) ----
  if (tid == 0)
    __hip_atomic_fetch_add(&ctrl[(128u + (unsigned)(bid & 15)) * 16u], 1ull,
                           __ATOMIC_RELAXED, __HIP_MEMORY_SCOPE_AGENT);
  if (tid < 16) {
    for (;;) {
      unsigned long long v = cloadu(&ctrl[(128u + (unsigned)tid) * 16u]);
      v += __shfl_xor(v, 1, 64);  v += __shfl_xor(v, 2, 64);
      v += __shfl_xor(v, 4, 64);  v += __shfl_xor(v, 8, 64);
      if (v >= (unsigned long long)NBLK) break;
      __builtin_amdgcn_s_sleep(1);
    }
  }
  __syncthreads();

  const double WOPT = 2.0 / (1.0 + 3.14159265358979323846 / 66.0);
  const int zmc  = (z >= 1) ? (z - 1) : 0;
  const int zpc  = (z <= NI - 2) ? (z + 1) : (NI - 1);
  const int zm2c = (z >= 2) ? (z - 2) : 0;
  const int zp2c = (z <= NI - 3) ? (z + 2) : (NI - 1);

  int itout = 0;
  double dvout = 0.0;

  for (int t = 1; t <= 555; ++t) {
    const float* __restrict__ prold = (t & 1) ? pr0 : pr1;  // pr[(t-1)&1]
    float* __restrict__ prcur       = (t & 1) ? pr1 : pr0;  // pr[t&1]

    // ---- start-of-iter: flag waits (z+-1, z+-2) || ring poll + stop ----
    if (t > 1) {
      const int g = t - 2;
      if (wid == 0 && lane < 4) {
        int d = (lane < 2) ? 1 : 2;
        int nb = z + ((lane & 1) ? d : -d);
        if (nb >= 0 && nb < NBLK) {
          while (cloadu(&ctrl[(276u + (unsigned)nb) * 16u])
                 < (unsigned long long)(t - 1))
            __builtin_amdgcn_s_sleep(1);
        }
      }
      if (g >= 1 && wid == 1 && lane < 16) {
        const int r = g & 7;
        const unsigned n = ((unsigned)g + 7u) >> 3;
        const unsigned long long t64 =
            ((unsigned long long)NBLK * n) << 44;
        unsigned long long v;
        for (;;) {
          v = cloadu(&ctrl[((unsigned)r * 16u + (unsigned)lane) * 16u]);
          v += __shfl_xor(v, 1, 64);  v += __shfl_xor(v, 2, 64);
          v += __shfl_xor(v, 4, 64);  v += __shfl_xor(v, 8, 64);
          if (v >= t64) break;
          __builtin_amdgcn_s_sleep(1);
        }
        if (lane == 0) {
          unsigned long long cum = v & MASK44;
          sh_dv = (double)(cum - prevs[r]) * (1.0 / 1048576.0);
          prevs[r] = cum;
        }
      }
      __syncthreads();
      if (g >= 1) {
        double dvg = sh_dv;
        if (!((dvg >= 0.05) && (g <= 500))) { itout = g; dvout = dvg; break; }
      }
    }

    // ---- stage channels into LDS: z+-1 full halves + z+-2 far entries,
    //      max MLP (all loads to registers, then all LDS writes) ----
    {
      const float* __restrict__ srcm = prold + (size_t)zmc * HPL;
      const float* __restrict__ srcp = prold + (size_t)zpc * HPL;
      const float* __restrict__ sm2  = prold + (size_t)zm2c * HPL;
      const float* __restrict__ sp2  = prold + (size_t)zp2c * HPL;
      const bool t130 = (tid < HPL - 2048);   // 130 tail threads
      float a0 = 0, a1 = 0, a2 = 0, b0 = 0, b1 = 0, b2 = 0, fm = 0, fp = 0;
      a0 = cloadf(&srcm[tid]);
      a1 = cloadf(&srcm[tid + 1024]);
      if (t130) a2 = cloadf(&srcm[tid + 2048]);
      b0 = cloadf(&srcp[tid]);
      b1 = cloadf(&srcp[tid + 1024]);
      if (t130) b2 = cloadf(&srcp[tid + 2048]);
      if (tid < nHm) fm = cloadf(&sm2[(int)hm[tid] >> 1]);
      if (tid < nHp) fp = cloadf(&sp2[(int)hp[tid] >> 1]);
      CM[tid] = a0; CM[tid + 1024] = a1; if (t130) CM[tid + 2048] = a2;
      CP[tid] = b0; CP[tid + 1024] = b1; if (t130) CP[tid + 2048] = b2;
      if (tid < nHm) FM[tid] = fm;
      if (tid < nHp) FP[tid] = fp;
    }
    __syncthreads();

    double acc = 0.0;
    // ====== BLACK own sweep (crosses from staged LDS, r20-identical) ======
    for (int p = tid; p < cntB; p += NTHR) {
      const unsigned u = lsB[p];
      const int o = (int)(u & 0xFFFFu);
      const int c = (int)(u >> 16);
      double fzm = (double)CM[c];
      double fzp = (double)CP[c];
      double xi = P1[o];
      double nb = ((((P1[o - 1] + P1[o + 1]) + P1[o - NJK]) + P1[o + NJK])
                  + fzm) + fzp;
      double adj = (WOPT * (nb - 6.0 * xi)) / 6.0;
      P1[o] = xi + adj;
      acc += fabs(adj);
    }
    // ====== halo-black updates (LDS only; disjoint from black sweep) ======
    for (int i = tid; i < nHm; i += NTHR) {
      const int o = (int)hm[i];
      const int c = o >> 1;
      double x = XBm[i];
      double nb = (((((double)CM[(o - 1) >> 1] + (double)CM[(o + 1) >> 1])
                    + (double)CM[c - 33]) + (double)CM[c + 33])
                    + (double)FM[i]) + P1[o];
      XBm[i] = x + (WOPT * (nb - 6.0 * x)) / 6.0;
    }
    for (int i = tid; i < nHp; i += NTHR) {
      const int o = (int)hp[i];
      const int c = o >> 1;
      double x = XBp[i];
      double nb = (((((double)CP[(o - 1) >> 1] + (double)CP[(o + 1) >> 1])
                    + (double)CP[c - 33]) + (double)CP[c + 33])
                    + P1[o]) + (double)FP[i];
      XBp[i] = x + (WOPT * (nb - 6.0 * x)) / 6.0;
    }
    __syncthreads();   // black P1 + XB visible

    // ====== RED own sweep: crosses from XB (LDS); inline publish ======
    {
      float* __restrict__ wpub = prcur + (size_t)z * HPL;
      for (int p = tid; p < cntR; p += NTHR) {
        const unsigned u = lsR[p];
        const int o = (int)(u & 0xFFFFu);
        const int c = (int)(u >> 16);
        const unsigned a2 = auxR[p];
        const unsigned im = a2 & 0xFFFFu, ip = a2 >> 16;
        double fzm = (im & 0x8000u) ? (double)(im & 1u) : XBm[im];
        double fzp = (ip & 0x8000u) ? (double)(ip & 1u) : XBp[ip];
        double xi = P1[o];
        double nb = ((((P1[o - 1] + P1[o + 1]) + P1[o - NJK]) + P1[o + NJK])
                    + fzm) + fzp;
        double adj = (WOPT * (nb - 6.0 * xi)) / 6.0;
        double v = xi + adj;
        P1[o] = v;
        cstoref(&wpub[c], (float)v);
        acc += fabs(adj);
      }
    }

    // ---- dv reduce (fixed order) + red flag + ring post ----
    double a = acc;
    #pragma unroll
    for (int m = 32; m >= 1; m >>= 1) a += __shfl_xor(a, m, 64);
    if (lane == 0) redw[wid] = a;
    __syncthreads();                       // drains publishes; redw ready
    if (tid == 0) {
      double s = redw[0];
      #pragma unroll
      for (int w = 1; w < NW; ++w) s += redw[w];
      cstoreu(&ctrl[(276u + (unsigned)bid) * 16u], (unsigned long long)t);
      __hip_atomic_fetch_add(
          &ctrl[(((unsigned)t & 7u) * 16u + (unsigned)(bid & 15)) * 16u],
          CNT1 + (unsigned long long)(s * 1048576.0 + 0.5),
          __ATOMIC_RELAXED, __HIP_MEMORY_SCOPE_AGENT);
    }
  }

  // ---- epilogue: lap straight from LDS (crop pad), + iters + dv ----
  {
    const int vb = (z >= 66) ? 1 : 0;
    const int pz = z - 66 * vb;
    if (pz >= 1 && pz <= 64) {
      float* ob = out + ((size_t)vb * 64 + (pz - 1)) * 4096;
      for (int t2 = tid; t2 < 4096; t2 += NTHR) {
        int jj = t2 >> 6, kk = t2 & 63;
        ob[t2] = (float)P1[NJK * (jj + 1) + (kk + 1)];
      }
    }
    if (z == 0 && tid == 0) {
      out[NOUT]     = (float)itout;
      out[NOUT + 1] = (float)dvout;
    }
  }
}

extern "C" void kernel_launch(void* const* d_in, const int* in_sizes, int n_in,
                              void* d_out, int out_size, void* d_ws, size_t ws_size,
                              hipStream_t stream) {
  const float* img = (const float*)d_in[0];
  float* out = (float*)d_out;
  float* pr0 = (float*)d_ws;
  float* pr1 = pr0 + (size_t)NI * HPL;
  unsigned long long* ctrl = (unsigned long long*)(pr1 + (size_t)NI * HPL);

  sor_init_ctrl<<<1, 256, 0, stream>>>(ctrl);
  sor_main<<<NBLK, NTHR, 0, stream>>>(img, pr0, pr1, ctrl, out);
}